// Round 8
// baseline (113.958 us; speedup 1.0000x reference)
//
#include <hip/hip_runtime.h>
#include <math.h>

#define BB 2
#define CC 256
#define GG 8
#define DD 32
#define HH 48
#define WW 48
#define HWSZ (HH*WW)        /* 2304 */
#define NHW (BB*HWSZ)       /* 4608 */
#define TOT (BB*CC*HWSZ)    /* 1179648 */
#define NBG (BB*GG)         /* 16 */
/* 1/sqrt(32) * log2(e): Q pre-scale so softmax runs in exp2 domain */
#define ATTN_SCALE (0.17677669529663687f * 1.4426950408889634f)

__device__ __align__(16) short g_q[NBG*HWSZ*DD];   // [bg][n][d] bf16, pre-scaled
__device__ __align__(16) short g_k[NBG*HWSZ*DD];   // [bg][n][d] bf16
__device__ __align__(16) short g_v[NBG*DD*HWSZ];   // [bg][d][n] bf16
__device__ __align__(16) float g_o[TOT];
__device__ __align__(16) short g_wq[GG*9*2*16*32]; // [g][tap][mh][l15][ci] bf16
__device__ __align__(16) short g_wk[CC*DD];        // [c][ci] bf16
__device__ __align__(16) short g_wv[CC*DD];        // [c][ci] bf16

typedef __attribute__((ext_vector_type(8))) short bf16x8;
typedef __attribute__((ext_vector_type(4))) short s16x4;
typedef __attribute__((ext_vector_type(4))) float f32x4;

__device__ __forceinline__ short f2bf(float f) {
    union { float f; unsigned u; } uf; uf.f = f;
    unsigned r = uf.u + 0x7fff + ((uf.u >> 16) & 1);  // RNE
    return (short)(r >> 16);
}
__device__ __forceinline__ short f2bf_rhu(float f) {   // round-half-up (cheap, P only)
    union { float f; unsigned u; } uf; uf.f = f;
    return (short)((uf.u + 0x8000u) >> 16);
}

// ---------------- weight pre-pack ----------------
__global__ __launch_bounds__(256) void pack_w(
    const float* __restrict__ Wq, const float* __restrict__ Wk,
    const float* __restrict__ Wv)
{
    int t = blockIdx.x * 256 + threadIdx.x;
    if (t < CC*DD*9) {                       // 73728
        int c = t / 288, r = t % 288, ci = r / 9, tap = r % 9;
        int g = c >> 5, mh = (c >> 4) & 1, l = c & 15;
        g_wq[(((g*9 + tap)*2 + mh)*16 + l)*32 + ci] = f2bf(Wq[t]);
    } else if (t < CC*DD*9 + CC*DD) {
        int i = t - CC*DD*9;
        g_wk[i] = f2bf(Wk[i]);
    } else if (t < CC*DD*9 + 2*CC*DD) {
        int i = t - CC*DD*9 - CC*DD;
        g_wv[i] = f2bf(Wv[i]);
    }
}

// ---------------- conv via implicit-GEMM MFMA: 576 one-wave blocks ----------------
// block = 1 wave = 64p output tile; 4-row LDS window; no __syncthreads.
__global__ __launch_bounds__(64) void conv_mfma(
    const float* __restrict__ x,
    const float* __restrict__ bq, const float* __restrict__ bk,
    const float* __restrict__ bv)
{
    __shared__ __align__(16) short xt[4*48*40];   // [row][col][ci] pad 40

    int lane = threadIdx.x;
    int bg = blockIdx.x & 15;        // XCD clustering
    int pt = blockIdx.x >> 4;        // 0..35, 64-position tile
    int p0 = pt * 64;
    int b = bg >> 3, g = bg & 7;
    int r0 = p0 / 48 - 1;            // 4 staged rows r0..r0+3 (may be -1 / 48)
    const float* xb = x + ((size_t)(b*CC + g*DD)) * HWSZ;

    // stage 4 rows x 48 cols x 32 ci (zero out-of-range rows); wave-private
    #pragma unroll 4
    for (int i = 0; i < 96; ++i) {
        int cell = lane + i * 64;    // 6144 = 32ci * 192rc
        int ci = cell / 192;
        int rc = cell % 192;
        int row = r0 + rc / 48, col = rc % 48;
        float v = (row >= 0 && row < 48) ? xb[(size_t)ci*HWSZ + row*48 + col] : 0.f;
        xt[rc*40 + ci] = f2bf(v);
    }
    // no barrier: same-wave DS ops are in-order

    int l15 = lane & 15, lg = lane >> 4;

    bf16x8 aq[9][2], ak[2], av[2];
    const short* wqg = g_wq + g*9*2*16*32;
    #pragma unroll
    for (int tap = 0; tap < 9; ++tap)
        #pragma unroll
        for (int mh = 0; mh < 2; ++mh)
            aq[tap][mh] = *(const bf16x8*)&wqg[((tap*2 + mh)*16 + l15)*32 + lg*8];
    #pragma unroll
    for (int mh = 0; mh < 2; ++mh) {
        ak[mh] = *(const bf16x8*)&g_wk[(g*32 + mh*16 + l15)*32 + lg*8];
        av[mh] = *(const bf16x8*)&g_wv[(g*32 + mh*16 + l15)*32 + lg*8];
    }
    float bqv[2][4], bkv[2][4], bvv[2][4];
    #pragma unroll
    for (int mh = 0; mh < 2; ++mh)
        #pragma unroll
        for (int j = 0; j < 4; ++j) {
            int c = g*32 + mh*16 + lg*4 + j;
            bqv[mh][j] = bq[c]; bkv[mh][j] = bk[c]; bvv[mh][j] = bv[c];
        }

    size_t qkb = (size_t)bg * HWSZ * DD;
    size_t vb  = (size_t)bg * DD * HWSZ;
    const f32x4 zero = {0.f,0.f,0.f,0.f};

    #pragma unroll
    for (int nf = 0; nf < 4; ++nf) {
        int n = p0 + nf*16 + l15;
        int y = n / 48, xcol = n % 48;
        int cell = (y - r0) * 48 + xcol;
        f32x4 cq0 = zero, cq1 = zero, ck0 = zero, ck1 = zero, cv0 = zero, cv1 = zero;
        #pragma unroll
        for (int tap = 0; tap < 9; ++tap) {
            int dy = tap / 3 - 1, dx = tap % 3 - 1;
            int xc = xcol + dx;
            bool ok = (unsigned)xc < 48u;
            int idx = ok ? (cell + dy*48 + dx)*40 + lg*8 : lg*8;
            bf16x8 bx = *(const bf16x8*)&xt[idx];
            if (!ok) bx = bf16x8{0,0,0,0,0,0,0,0};
            cq0 = __builtin_amdgcn_mfma_f32_16x16x32_bf16(aq[tap][0], bx, cq0, 0, 0, 0);
            cq1 = __builtin_amdgcn_mfma_f32_16x16x32_bf16(aq[tap][1], bx, cq1, 0, 0, 0);
            if (tap == 4) {
                ck0 = __builtin_amdgcn_mfma_f32_16x16x32_bf16(ak[0], bx, ck0, 0, 0, 0);
                ck1 = __builtin_amdgcn_mfma_f32_16x16x32_bf16(ak[1], bx, ck1, 0, 0, 0);
                cv0 = __builtin_amdgcn_mfma_f32_16x16x32_bf16(av[0], bx, cv0, 0, 0, 0);
                cv1 = __builtin_amdgcn_mfma_f32_16x16x32_bf16(av[1], bx, cv1, 0, 0, 0);
            }
        }
        #pragma unroll
        for (int mh = 0; mh < 2; ++mh) {
            f32x4 aQ = mh ? cq1 : cq0;
            f32x4 aK = mh ? ck1 : ck0;
            f32x4 aV = mh ? cv1 : cv0;
            s16x4 pq, pk;
            #pragma unroll
            for (int j = 0; j < 4; ++j) {
                pq[j] = f2bf((aQ[j] + bqv[mh][j]) * ATTN_SCALE);
                pk[j] = f2bf(aK[j] + bkv[mh][j]);
            }
            *(s16x4*)&g_q[qkb + (size_t)n*32 + mh*16 + lg*4] = pq;
            *(s16x4*)&g_k[qkb + (size_t)n*32 + mh*16 + lg*4] = pk;
            #pragma unroll
            for (int j = 0; j < 4; ++j)
                g_v[vb + (size_t)(mh*16 + lg*4 + j)*HWSZ + n] = f2bf(aV[j] + bvv[mh][j]);
        }
    }
}

// ---------------- flash attention: 2-tile interleaved ILP, no online max ----------------
// 1 wave/block, 16 q/wave; 18 iterations x 2 independent 64-key chains.
__global__ __launch_bounds__(64) void attn_mfma()
{
    __shared__ __align__(16) short p_lds[2][16][72];

    int lane = threadIdx.x;
    int l15 = lane & 15;
    int lg  = lane >> 4;
    int bg = blockIdx.x & 15;
    int qt = blockIdx.x >> 4;        // 0..143

    const short* qg = g_q + (size_t)bg * HWSZ * DD;
    const short* kg = g_k + (size_t)bg * HWSZ * DD;
    const short* vg = g_v + (size_t)bg * DD * HWSZ;

    bf16x8 aq = *(const bf16x8*)&qg[(size_t)(qt*16 + l15)*32 + lg*8];

    f32x4 oc0 = {0.f,0.f,0.f,0.f}, oc1 = {0.f,0.f,0.f,0.f};
    const f32x4 zero = {0.f,0.f,0.f,0.f};
    float lsum = 0.f;

    // current-tile fragments: K0/V0 = tile m0, K1/V1 = tile m0+64
    bf16x8 K0[4], K1[4], V0[4], V1[4];
    #pragma unroll
    for (int kb = 0; kb < 4; ++kb) {
        K0[kb] = *(const bf16x8*)&kg[(size_t)(kb*16 + l15)*32 + lg*8];
        K1[kb] = *(const bf16x8*)&kg[(size_t)(64 + kb*16 + l15)*32 + lg*8];
    }
    #pragma unroll
    for (int h = 0; h < 2; ++h)
        #pragma unroll
        for (int w = 0; w < 2; ++w) {
            V0[h*2+w] = *(const bf16x8*)&vg[(size_t)(w*16 + l15)*HWSZ + h*32 + lg*8];
            V1[h*2+w] = *(const bf16x8*)&vg[(size_t)(w*16 + l15)*HWSZ + 64 + h*32 + lg*8];
        }

    for (int it = 0; it < 18; ++it) {
        int m0 = it * 128;
        int ma = (m0 + 128 < HWSZ) ? m0 + 128 : 0;   // next even tile
        int mb = ma + 64;                            // next odd tile

        // K prefetch into dedicated regs (full-iteration slack)
        bf16x8 nK0[4], nK1[4];
        #pragma unroll
        for (int kb = 0; kb < 4; ++kb) {
            nK0[kb] = *(const bf16x8*)&kg[(size_t)(ma + kb*16 + l15)*32 + lg*8];
            nK1[kb] = *(const bf16x8*)&kg[(size_t)(mb + kb*16 + l15)*32 + lg*8];
        }

        // QK^T both chains (independent)
        f32x4 sA[4], sB[4];
        #pragma unroll
        for (int kb = 0; kb < 4; ++kb)
            sA[kb] = __builtin_amdgcn_mfma_f32_16x16x32_bf16(K0[kb], aq, zero, 0, 0, 0);
        #pragma unroll
        for (int kb = 0; kb < 4; ++kb)
            sB[kb] = __builtin_amdgcn_mfma_f32_16x16x32_bf16(K1[kb], aq, zero, 0, 0, 0);

        // exp2 + pack + LDS write, chain A then B (VALU overlaps MFMA latency)
        #pragma unroll
        for (int kb = 0; kb < 4; ++kb) {
            s16x4 pk;
            #pragma unroll
            for (int j = 0; j < 4; ++j) {
                float p = exp2f(sA[kb][j]);
                lsum += p;
                pk[j] = f2bf_rhu(p);
            }
            *(s16x4*)&p_lds[0][l15][kb*16 + lg*4] = pk;
        }
        #pragma unroll
        for (int kb = 0; kb < 4; ++kb) {
            s16x4 pk;
            #pragma unroll
            for (int j = 0; j < 4; ++j) {
                float p = exp2f(sB[kb][j]);
                lsum += p;
                pk[j] = f2bf_rhu(p);
            }
            *(s16x4*)&p_lds[1][l15][kb*16 + lg*4] = pk;
        }

        // PV chain A then B (same-wave DS in-order; no barrier)
        #pragma unroll
        for (int half = 0; half < 2; ++half) {
            bf16x8 pa = *(const bf16x8*)&p_lds[0][l15][half*32 + lg*8];
            oc0 = __builtin_amdgcn_mfma_f32_16x16x32_bf16(V0[half*2+0], pa, oc0, 0, 0, 0);
            oc1 = __builtin_amdgcn_mfma_f32_16x16x32_bf16(V0[half*2+1], pa, oc1, 0, 0, 0);
        }
        #pragma unroll
        for (int half = 0; half < 2; ++half) {
            bf16x8 pa = *(const bf16x8*)&p_lds[1][l15][half*32 + lg*8];
            oc0 = __builtin_amdgcn_mfma_f32_16x16x32_bf16(V1[half*2+0], pa, oc0, 0, 0, 0);
            oc1 = __builtin_amdgcn_mfma_f32_16x16x32_bf16(V1[half*2+1], pa, oc1, 0, 0, 0);
        }

        // V double-buffer reload (WAR after PV consumed old V)
        #pragma unroll
        for (int h = 0; h < 2; ++h)
            #pragma unroll
            for (int w = 0; w < 2; ++w) {
                V0[h*2+w] = *(const bf16x8*)&vg[(size_t)(w*16 + l15)*HWSZ + ma + h*32 + lg*8];
                V1[h*2+w] = *(const bf16x8*)&vg[(size_t)(w*16 + l15)*HWSZ + mb + h*32 + lg*8];
            }
        #pragma unroll
        for (int kb = 0; kb < 4; ++kb) { K0[kb] = nK0[kb]; K1[kb] = nK1[kb]; }
    }

    // single denominator reduction (q = l15 column, across lg groups)
    lsum += __shfl_xor(lsum, 16, 64);
    lsum += __shfl_xor(lsum, 32, 64);
    float inv = 1.f / lsum;

    size_t ob = (size_t)bg * DD * HWSZ;
    int n = qt * 16 + l15;
    #pragma unroll
    for (int j = 0; j < 4; ++j) {
        g_o[ob + (size_t)(lg*4 + j) * HWSZ + n]      = oc0[j] * inv;
        g_o[ob + (size_t)(16 + lg*4 + j) * HWSZ + n] = oc1[j] * inv;
    }
}

// ---------------- BN (training-mode batch stats) + affine + ReLU ----------------
__global__ __launch_bounds__(256) void bn_relu(
    const float* __restrict__ gamma, const float* __restrict__ beta,
    float* __restrict__ out)
{
    __shared__ float rs[4], rss[4];
    __shared__ float smean, sinv;
    int c = blockIdx.x;
    int tid = threadIdx.x;
    const float* o0 = g_o + (size_t)c * HWSZ;
    const float* o1 = g_o + (size_t)(CC + c) * HWSZ;

    float s = 0.f, ss = 0.f;
    for (int i = tid; i < HWSZ; i += 256) {
        float v0 = o0[i], v1 = o1[i];
        s += v0 + v1;
        ss += v0 * v0 + v1 * v1;
    }
    #pragma unroll
    for (int off = 32; off; off >>= 1) {
        s  += __shfl_down(s, off, 64);
        ss += __shfl_down(ss, off, 64);
    }
    int wid = tid >> 6, lane = tid & 63;
    if (lane == 0) { rs[wid] = s; rss[wid] = ss; }
    __syncthreads();
    if (tid == 0) {
        float ts  = rs[0] + rs[1] + rs[2] + rs[3];
        float tss = rss[0] + rss[1] + rss[2] + rss[3];
        float mean = ts / (float)NHW;
        float var  = tss / (float)NHW - mean * mean;
        smean = mean;
        sinv  = rsqrtf(var + 1e-5f);
    }
    __syncthreads();
    float mean = smean, inv = sinv;
    float ga = gamma[c], be = beta[c];
    float* out0 = out + (size_t)c * HWSZ;
    float* out1 = out + (size_t)(CC + c) * HWSZ;
    for (int i = tid; i < HWSZ; i += 256) {
        float v0 = (o0[i] - mean) * inv * ga + be;
        float v1 = (o1[i] - mean) * inv * ga + be;
        out0[i] = fmaxf(v0, 0.f);
        out1[i] = fmaxf(v1, 0.f);
    }
}

extern "C" void kernel_launch(void* const* d_in, const int* in_sizes, int n_in,
                              void* d_out, int out_size, void* d_ws, size_t ws_size,
                              hipStream_t stream)
{
    const float* x     = (const float*)d_in[0];
    const float* Wq    = (const float*)d_in[1];
    const float* bq    = (const float*)d_in[2];
    const float* Wk    = (const float*)d_in[3];
    const float* bk    = (const float*)d_in[4];
    const float* Wv    = (const float*)d_in[5];
    const float* bv    = (const float*)d_in[6];
    const float* gamma = (const float*)d_in[7];
    const float* beta  = (const float*)d_in[8];
    float* out = (float*)d_out;

    pack_w<<<(CC*DD*9 + 2*CC*DD + 255) / 256, 256, 0, stream>>>(Wq, Wk, Wv);
    conv_mfma<<<NBG * 36, 64, 0, stream>>>(x, bq, bk, bv);
    attn_mfma<<<NBG * 144, 64, 0, stream>>>();
    bn_relu<<<CC, 256, 0, stream>>>(gamma, beta, out);
}

// Round 9
// 101.462 us; speedup vs baseline: 1.1232x; 1.1232x over previous
//
#include <hip/hip_runtime.h>
#include <math.h>

#define BB 2
#define CC 256
#define GG 8
#define DD 32
#define HH 48
#define WW 48
#define HWSZ (HH*WW)        /* 2304 */
#define NHW (BB*HWSZ)       /* 4608 */
#define TOT (BB*CC*HWSZ)    /* 1179648 */
#define NBG (BB*GG)         /* 16 */
#define KSPLIT 4
#define KSEG (HWSZ/KSPLIT)  /* 576 keys per split = 9 tiles */
/* 1/sqrt(32) * log2(e): Q pre-scale so softmax runs in exp2 domain */
#define ATTN_SCALE (0.17677669529663687f * 1.4426950408889634f)

__device__ __align__(16) short g_q[NBG*HWSZ*DD];   // [bg][n][d] bf16, pre-scaled
__device__ __align__(16) short g_k[NBG*HWSZ*DD];   // [bg][n][d] bf16
__device__ __align__(16) short g_v[NBG*DD*HWSZ];   // [bg][d][n] bf16
__device__ __align__(16) float g_po[KSPLIT*NBG*DD*HWSZ]; // partial O (un-normalized)
__device__ __align__(16) float g_pl[KSPLIT*NBG*HWSZ];    // partial lsum
__device__ __align__(16) short g_wq[GG*9*2*16*32]; // [g][tap][mh][l15][ci] bf16
__device__ __align__(16) short g_wk[CC*DD];        // [c][ci] bf16
__device__ __align__(16) short g_wv[CC*DD];        // [c][ci] bf16

typedef __attribute__((ext_vector_type(8))) short bf16x8;
typedef __attribute__((ext_vector_type(4))) short s16x4;
typedef __attribute__((ext_vector_type(4))) float f32x4;

__device__ __forceinline__ short f2bf(float f) {
    union { float f; unsigned u; } uf; uf.f = f;
    unsigned r = uf.u + 0x7fff + ((uf.u >> 16) & 1);  // RNE
    return (short)(r >> 16);
}
__device__ __forceinline__ short f2bf_rhu(float f) {   // round-half-up (cheap, P only)
    union { float f; unsigned u; } uf; uf.f = f;
    return (short)((uf.u + 0x8000u) >> 16);
}

// ---------------- weight pre-pack ----------------
__global__ __launch_bounds__(256) void pack_w(
    const float* __restrict__ Wq, const float* __restrict__ Wk,
    const float* __restrict__ Wv)
{
    int t = blockIdx.x * 256 + threadIdx.x;
    if (t < CC*DD*9) {                       // 73728
        int c = t / 288, r = t % 288, ci = r / 9, tap = r % 9;
        int g = c >> 5, mh = (c >> 4) & 1, l = c & 15;
        g_wq[(((g*9 + tap)*2 + mh)*16 + l)*32 + ci] = f2bf(Wq[t]);
    } else if (t < CC*DD*9 + CC*DD) {
        int i = t - CC*DD*9;
        g_wk[i] = f2bf(Wk[i]);
    } else if (t < CC*DD*9 + 2*CC*DD) {
        int i = t - CC*DD*9 - CC*DD;
        g_wv[i] = f2bf(Wv[i]);
    }
}

// ---------------- conv via implicit-GEMM MFMA (R7 256-thread version) ----------------
__global__ __launch_bounds__(256) void conv_mfma(
    const float* __restrict__ x,
    const float* __restrict__ bq, const float* __restrict__ bk,
    const float* __restrict__ bv)
{
    __shared__ __align__(16) short xt[8*48*40];   // [row][col][ci] pad 40

    int tid = threadIdx.x;
    int bg = blockIdx.x / 9;
    int pt = blockIdx.x % 9;
    int p0 = pt * 256;
    int b = bg >> 3, g = bg & 7;
    int r0 = p0 / 48 - 1;
    const float* xb = x + ((size_t)(b*CC + g*DD)) * HWSZ;

    for (int i = 0; i < 48; ++i) {
        int cell = tid + i * 256;
        int ci = cell / 384;
        int rc = cell % 384;
        int row = r0 + rc / 48, col = rc % 48;
        float v = (row >= 0 && row < 48) ? xb[(size_t)ci*HWSZ + row*48 + col] : 0.f;
        xt[rc*40 + ci] = f2bf(v);
    }
    __syncthreads();

    int lane = tid & 63, wave = tid >> 6;
    int l15 = lane & 15, lg = lane >> 4;

    bf16x8 aq[9][2], ak[2], av[2];
    const short* wqg = g_wq + g*9*2*16*32;
    #pragma unroll
    for (int tap = 0; tap < 9; ++tap)
        #pragma unroll
        for (int mh = 0; mh < 2; ++mh)
            aq[tap][mh] = *(const bf16x8*)&wqg[((tap*2 + mh)*16 + l15)*32 + lg*8];
    #pragma unroll
    for (int mh = 0; mh < 2; ++mh) {
        ak[mh] = *(const bf16x8*)&g_wk[(g*32 + mh*16 + l15)*32 + lg*8];
        av[mh] = *(const bf16x8*)&g_wv[(g*32 + mh*16 + l15)*32 + lg*8];
    }
    float bqv[2][4], bkv[2][4], bvv[2][4];
    #pragma unroll
    for (int mh = 0; mh < 2; ++mh)
        #pragma unroll
        for (int j = 0; j < 4; ++j) {
            int c = g*32 + mh*16 + lg*4 + j;
            bqv[mh][j] = bq[c]; bkv[mh][j] = bk[c]; bvv[mh][j] = bv[c];
        }

    int p0w = p0 + wave * 64;
    size_t qkb = (size_t)bg * HWSZ * DD;
    size_t vb  = (size_t)bg * DD * HWSZ;
    const f32x4 zero = {0.f,0.f,0.f,0.f};

    #pragma unroll
    for (int nf = 0; nf < 4; ++nf) {
        int n = p0w + nf*16 + l15;
        int y = n / 48, xcol = n % 48;
        int cell = (y - r0) * 48 + xcol;
        f32x4 cq0 = zero, cq1 = zero, ck0 = zero, ck1 = zero, cv0 = zero, cv1 = zero;
        #pragma unroll
        for (int tap = 0; tap < 9; ++tap) {
            int dy = tap / 3 - 1, dx = tap % 3 - 1;
            int xc = xcol + dx;
            bool ok = (unsigned)xc < 48u;
            int idx = ok ? (cell + dy*48 + dx)*40 + lg*8 : lg*8;
            bf16x8 bx = *(const bf16x8*)&xt[idx];
            if (!ok) bx = bf16x8{0,0,0,0,0,0,0,0};
            cq0 = __builtin_amdgcn_mfma_f32_16x16x32_bf16(aq[tap][0], bx, cq0, 0, 0, 0);
            cq1 = __builtin_amdgcn_mfma_f32_16x16x32_bf16(aq[tap][1], bx, cq1, 0, 0, 0);
            if (tap == 4) {
                ck0 = __builtin_amdgcn_mfma_f32_16x16x32_bf16(ak[0], bx, ck0, 0, 0, 0);
                ck1 = __builtin_amdgcn_mfma_f32_16x16x32_bf16(ak[1], bx, ck1, 0, 0, 0);
                cv0 = __builtin_amdgcn_mfma_f32_16x16x32_bf16(av[0], bx, cv0, 0, 0, 0);
                cv1 = __builtin_amdgcn_mfma_f32_16x16x32_bf16(av[1], bx, cv1, 0, 0, 0);
            }
        }
        #pragma unroll
        for (int mh = 0; mh < 2; ++mh) {
            f32x4 aQ = mh ? cq1 : cq0;
            f32x4 aK = mh ? ck1 : ck0;
            f32x4 aV = mh ? cv1 : cv0;
            s16x4 pq, pk;
            #pragma unroll
            for (int j = 0; j < 4; ++j) {
                pq[j] = f2bf((aQ[j] + bqv[mh][j]) * ATTN_SCALE);
                pk[j] = f2bf(aK[j] + bkv[mh][j]);
            }
            *(s16x4*)&g_q[qkb + (size_t)n*32 + mh*16 + lg*4] = pq;
            *(s16x4*)&g_k[qkb + (size_t)n*32 + mh*16 + lg*4] = pk;
            #pragma unroll
            for (int j = 0; j < 4; ++j)
                g_v[vb + (size_t)(mh*16 + lg*4 + j)*HWSZ + n] = f2bf(aV[j] + bvv[mh][j]);
        }
    }
}

// ---------------- attention: key-split partials (additive, no online max) ----------------
// grid 16bg x 144qt x 4ks = 9216 one-wave blocks; each wave: 16 q, 576 keys.
__global__ __launch_bounds__(64) void attn_mfma()
{
    __shared__ __align__(16) short p_lds[16][72];

    int lane = threadIdx.x;
    int l15 = lane & 15;
    int lg  = lane >> 4;
    int bg = blockIdx.x & 15;        // XCD clustering
    int r  = blockIdx.x >> 4;        // 0..575
    int ks = r & 3;
    int qt = r >> 2;                 // 0..143
    int k0 = ks * KSEG;

    const short* qg = g_q + (size_t)bg * HWSZ * DD;
    const short* kg = g_k + (size_t)bg * HWSZ * DD;
    const short* vg = g_v + (size_t)bg * DD * HWSZ;

    bf16x8 aq = *(const bf16x8*)&qg[(size_t)(qt*16 + l15)*32 + lg*8];

    f32x4 oc0 = {0.f,0.f,0.f,0.f}, oc1 = {0.f,0.f,0.f,0.f};
    const f32x4 zero = {0.f,0.f,0.f,0.f};
    float lsum = 0.f;

    // preload tile 0 of this split
    bf16x8 ck[4], cv[4];
    #pragma unroll
    for (int kb = 0; kb < 4; ++kb)
        ck[kb] = *(const bf16x8*)&kg[(size_t)(k0 + kb*16 + l15)*32 + lg*8];
    #pragma unroll
    for (int h = 0; h < 2; ++h)
        #pragma unroll
        for (int w = 0; w < 2; ++w)
            cv[h*2+w] = *(const bf16x8*)&vg[(size_t)(w*16 + l15)*HWSZ + k0 + h*32 + lg*8];

    for (int t = 0; t < KSEG/64; ++t) {
        int mm = k0 + ((t + 1 < KSEG/64) ? (t + 1) * 64 : 0);
        bf16x8 nk[4], nv[4];
        #pragma unroll
        for (int kb = 0; kb < 4; ++kb)
            nk[kb] = *(const bf16x8*)&kg[(size_t)(mm + kb*16 + l15)*32 + lg*8];
        #pragma unroll
        for (int h = 0; h < 2; ++h)
            #pragma unroll
            for (int w = 0; w < 2; ++w)
                nv[h*2+w] = *(const bf16x8*)&vg[(size_t)(w*16 + l15)*HWSZ + mm + h*32 + lg*8];

        // S^T = K·Q^T : lane holds S[q=l15][k=kb*16+lg*4+j]
        f32x4 s[4];
        #pragma unroll
        for (int kb = 0; kb < 4; ++kb)
            s[kb] = __builtin_amdgcn_mfma_f32_16x16x32_bf16(ck[kb], aq, zero, 0, 0, 0);

        // p = exp2(s); lane-local denominator; pack to LDS
        #pragma unroll
        for (int kb = 0; kb < 4; ++kb) {
            s16x4 pk;
            #pragma unroll
            for (int j = 0; j < 4; ++j) {
                float p = exp2f(s[kb][j]);
                lsum += p;
                pk[j] = f2bf_rhu(p);
            }
            *(s16x4*)&p_lds[l15][kb*16 + lg*4] = pk;
        }

        // PV (wave-private LDS, no barrier)
        #pragma unroll
        for (int half = 0; half < 2; ++half) {
            bf16x8 pa = *(const bf16x8*)&p_lds[l15][half*32 + lg*8];
            oc0 = __builtin_amdgcn_mfma_f32_16x16x32_bf16(cv[half*2+0], pa, oc0, 0, 0, 0);
            oc1 = __builtin_amdgcn_mfma_f32_16x16x32_bf16(cv[half*2+1], pa, oc1, 0, 0, 0);
        }

        #pragma unroll
        for (int kb = 0; kb < 4; ++kb) ck[kb] = nk[kb];
        #pragma unroll
        for (int i = 0; i < 4; ++i) cv[i] = nv[i];
    }

    // denominator over this split (q = l15 column, across lg)
    lsum += __shfl_xor(lsum, 16, 64);
    lsum += __shfl_xor(lsum, 32, 64);

    int n = qt * 16 + l15;
    size_t pb = (size_t)(ks * NBG + bg) * DD * HWSZ;
    #pragma unroll
    for (int j = 0; j < 4; ++j) {
        g_po[pb + (size_t)(lg*4 + j) * HWSZ + n]      = oc0[j];
        g_po[pb + (size_t)(16 + lg*4 + j) * HWSZ + n] = oc1[j];
    }
    if (lg == 0) g_pl[(size_t)(ks * NBG + bg) * HWSZ + n] = lsum;
}

// ---------------- combine partials + BN (batch stats) + affine + ReLU ----------------
__global__ __launch_bounds__(256) void bn_relu(
    const float* __restrict__ gamma, const float* __restrict__ beta,
    float* __restrict__ out)
{
    __shared__ float vbuf[2][HWSZ];           // combined attention output, 18.4 KB
    __shared__ float rs[4], rss[4];
    __shared__ float smean, sinv;
    int c = blockIdx.x;
    int tid = threadIdx.x;
    int g = c >> 5, d = c & 31;
    int bg0 = g, bg1 = 8 + g;                 // b=0,1

    float s = 0.f, ss = 0.f;
    for (int i = tid; i < HWSZ; i += 256) {
        float n0 = 0.f, d0 = 0.f, n1 = 0.f, d1 = 0.f;
        #pragma unroll
        for (int ks = 0; ks < KSPLIT; ++ks) {
            n0 += g_po[((size_t)(ks*NBG + bg0) * DD + d) * HWSZ + i];
            d0 += g_pl[(size_t)(ks*NBG + bg0) * HWSZ + i];
            n1 += g_po[((size_t)(ks*NBG + bg1) * DD + d) * HWSZ + i];
            d1 += g_pl[(size_t)(ks*NBG + bg1) * HWSZ + i];
        }
        float v0 = n0 / d0, v1 = n1 / d1;
        vbuf[0][i] = v0; vbuf[1][i] = v1;
        s += v0 + v1;
        ss += v0 * v0 + v1 * v1;
    }
    #pragma unroll
    for (int off = 32; off; off >>= 1) {
        s  += __shfl_down(s, off, 64);
        ss += __shfl_down(ss, off, 64);
    }
    int wid = tid >> 6, lane = tid & 63;
    if (lane == 0) { rs[wid] = s; rss[wid] = ss; }
    __syncthreads();
    if (tid == 0) {
        float ts  = rs[0] + rs[1] + rs[2] + rs[3];
        float tss = rss[0] + rss[1] + rss[2] + rss[3];
        float mean = ts / (float)NHW;
        float var  = tss / (float)NHW - mean * mean;
        smean = mean;
        sinv  = rsqrtf(var + 1e-5f);
    }
    __syncthreads();
    float mean = smean, inv = sinv;
    float ga = gamma[c], be = beta[c];
    float* out0 = out + (size_t)c * HWSZ;
    float* out1 = out + (size_t)(CC + c) * HWSZ;
    for (int i = tid; i < HWSZ; i += 256) {
        float v0 = (vbuf[0][i] - mean) * inv * ga + be;
        float v1 = (vbuf[1][i] - mean) * inv * ga + be;
        out0[i] = fmaxf(v0, 0.f);
        out1[i] = fmaxf(v1, 0.f);
    }
}

extern "C" void kernel_launch(void* const* d_in, const int* in_sizes, int n_in,
                              void* d_out, int out_size, void* d_ws, size_t ws_size,
                              hipStream_t stream)
{
    const float* x     = (const float*)d_in[0];
    const float* Wq    = (const float*)d_in[1];
    const float* bq    = (const float*)d_in[2];
    const float* Wk    = (const float*)d_in[3];
    const float* bk    = (const float*)d_in[4];
    const float* Wv    = (const float*)d_in[5];
    const float* bv    = (const float*)d_in[6];
    const float* gamma = (const float*)d_in[7];
    const float* beta  = (const float*)d_in[8];
    float* out = (float*)d_out;

    pack_w<<<(CC*DD*9 + 2*CC*DD + 255) / 256, 256, 0, stream>>>(Wq, Wk, Wv);
    conv_mfma<<<NBG * 9, 256, 0, stream>>>(x, bq, bk, bv);
    attn_mfma<<<NBG * 144 * KSPLIT, 64, 0, stream>>>();
    bn_relu<<<CC, 256, 0, stream>>>(gamma, beta, out);
}

// Round 10
// 101.455 us; speedup vs baseline: 1.1232x; 1.0001x over previous
//
#include <hip/hip_runtime.h>
#include <math.h>

#define BB 2
#define CC 256
#define GG 8
#define DD 32
#define HH 48
#define WW 48
#define HWSZ (HH*WW)        /* 2304 */
#define NHW (BB*HWSZ)       /* 4608 */
#define TOT (BB*CC*HWSZ)    /* 1179648 */
#define NBG (BB*GG)         /* 16 */
#define KSPLIT 4
#define KSEG (HWSZ/KSPLIT)  /* 576 keys per split = 9 tiles */
/* 1/sqrt(32) * log2(e): Q pre-scale so softmax runs in exp2 domain */
#define ATTN_SCALE (0.17677669529663687f * 1.4426950408889634f)

__device__ __align__(16) short g_q[NBG*HWSZ*DD];   // [bg][n][d] bf16, pre-scaled
__device__ __align__(16) short g_k[NBG*HWSZ*DD];   // [bg][n][d] bf16
__device__ __align__(16) short g_v[NBG*DD*HWSZ];   // [bg][d][n] bf16
__device__ __align__(16) float g_po[KSPLIT*NBG*DD*HWSZ]; // partial O (un-normalized)
__device__ __align__(16) float g_pl[KSPLIT*NBG*HWSZ];    // partial lsum
__device__ __align__(16) short g_wq[GG*9*2*16*32]; // [g][tap][mh][l15][ci] bf16
__device__ __align__(16) short g_wk[CC*DD];        // [c][ci] bf16
__device__ __align__(16) short g_wv[CC*DD];        // [c][ci] bf16

typedef __attribute__((ext_vector_type(8))) short bf16x8;
typedef __attribute__((ext_vector_type(4))) short s16x4;
typedef __attribute__((ext_vector_type(4))) float f32x4;

__device__ __forceinline__ short f2bf(float f) {
    union { float f; unsigned u; } uf; uf.f = f;
    unsigned r = uf.u + 0x7fff + ((uf.u >> 16) & 1);  // RNE
    return (short)(r >> 16);
}
__device__ __forceinline__ unsigned cvt_pk_bf16(float lo, float hi) {
    unsigned w;
    asm("v_cvt_pk_bf16_f32 %0, %1, %2" : "=v"(w) : "v"(lo), "v"(hi));
    return w;
}

// ---------------- weight pre-pack ----------------
__global__ __launch_bounds__(256) void pack_w(
    const float* __restrict__ Wq, const float* __restrict__ Wk,
    const float* __restrict__ Wv)
{
    int t = blockIdx.x * 256 + threadIdx.x;
    if (t < CC*DD*9) {                       // 73728
        int c = t / 288, r = t % 288, ci = r / 9, tap = r % 9;
        int g = c >> 5, mh = (c >> 4) & 1, l = c & 15;
        g_wq[(((g*9 + tap)*2 + mh)*16 + l)*32 + ci] = f2bf(Wq[t]);
    } else if (t < CC*DD*9 + CC*DD) {
        int i = t - CC*DD*9;
        g_wk[i] = f2bf(Wk[i]);
    } else if (t < CC*DD*9 + 2*CC*DD) {
        int i = t - CC*DD*9 - CC*DD;
        g_wv[i] = f2bf(Wv[i]);
    }
}

// ---------------- conv via implicit-GEMM MFMA ----------------
__global__ __launch_bounds__(256) void conv_mfma(
    const float* __restrict__ x,
    const float* __restrict__ bq, const float* __restrict__ bk,
    const float* __restrict__ bv)
{
    __shared__ __align__(16) short xt[8*48*40];   // [row][col][ci] pad 40

    int tid = threadIdx.x;
    int bg = blockIdx.x / 9;
    int pt = blockIdx.x % 9;
    int p0 = pt * 256;
    int b = bg >> 3, g = bg & 7;
    int r0 = p0 / 48 - 1;
    const float* xb = x + ((size_t)(b*CC + g*DD)) * HWSZ;

    for (int i = 0; i < 48; ++i) {
        int cell = tid + i * 256;
        int ci = cell / 384;
        int rc = cell % 384;
        int row = r0 + rc / 48, col = rc % 48;
        float v = (row >= 0 && row < 48) ? xb[(size_t)ci*HWSZ + row*48 + col] : 0.f;
        xt[rc*40 + ci] = f2bf(v);
    }
    __syncthreads();

    int lane = tid & 63, wave = tid >> 6;
    int l15 = lane & 15, lg = lane >> 4;

    bf16x8 aq[9][2], ak[2], av[2];
    const short* wqg = g_wq + g*9*2*16*32;
    #pragma unroll
    for (int tap = 0; tap < 9; ++tap)
        #pragma unroll
        for (int mh = 0; mh < 2; ++mh)
            aq[tap][mh] = *(const bf16x8*)&wqg[((tap*2 + mh)*16 + l15)*32 + lg*8];
    #pragma unroll
    for (int mh = 0; mh < 2; ++mh) {
        ak[mh] = *(const bf16x8*)&g_wk[(g*32 + mh*16 + l15)*32 + lg*8];
        av[mh] = *(const bf16x8*)&g_wv[(g*32 + mh*16 + l15)*32 + lg*8];
    }
    float bqv[2][4], bkv[2][4], bvv[2][4];
    #pragma unroll
    for (int mh = 0; mh < 2; ++mh)
        #pragma unroll
        for (int j = 0; j < 4; ++j) {
            int c = g*32 + mh*16 + lg*4 + j;
            bqv[mh][j] = bq[c]; bkv[mh][j] = bk[c]; bvv[mh][j] = bv[c];
        }

    int p0w = p0 + wave * 64;
    size_t qkb = (size_t)bg * HWSZ * DD;
    size_t vb  = (size_t)bg * DD * HWSZ;
    const f32x4 zero = {0.f,0.f,0.f,0.f};

    #pragma unroll
    for (int nf = 0; nf < 4; ++nf) {
        int n = p0w + nf*16 + l15;
        int y = n / 48, xcol = n % 48;
        int cell = (y - r0) * 48 + xcol;
        f32x4 cq0 = zero, cq1 = zero, ck0 = zero, ck1 = zero, cv0 = zero, cv1 = zero;
        #pragma unroll
        for (int tap = 0; tap < 9; ++tap) {
            int dy = tap / 3 - 1, dx = tap % 3 - 1;
            int xc = xcol + dx;
            bool ok = (unsigned)xc < 48u;
            int idx = ok ? (cell + dy*48 + dx)*40 + lg*8 : lg*8;
            bf16x8 bx = *(const bf16x8*)&xt[idx];
            if (!ok) bx = bf16x8{0,0,0,0,0,0,0,0};
            cq0 = __builtin_amdgcn_mfma_f32_16x16x32_bf16(aq[tap][0], bx, cq0, 0, 0, 0);
            cq1 = __builtin_amdgcn_mfma_f32_16x16x32_bf16(aq[tap][1], bx, cq1, 0, 0, 0);
            if (tap == 4) {
                ck0 = __builtin_amdgcn_mfma_f32_16x16x32_bf16(ak[0], bx, ck0, 0, 0, 0);
                ck1 = __builtin_amdgcn_mfma_f32_16x16x32_bf16(ak[1], bx, ck1, 0, 0, 0);
                cv0 = __builtin_amdgcn_mfma_f32_16x16x32_bf16(av[0], bx, cv0, 0, 0, 0);
                cv1 = __builtin_amdgcn_mfma_f32_16x16x32_bf16(av[1], bx, cv1, 0, 0, 0);
            }
        }
        #pragma unroll
        for (int mh = 0; mh < 2; ++mh) {
            f32x4 aQ = mh ? cq1 : cq0;
            f32x4 aK = mh ? ck1 : ck0;
            f32x4 aV = mh ? cv1 : cv0;
            s16x4 pq, pk;
            #pragma unroll
            for (int j = 0; j < 4; ++j) {
                pq[j] = f2bf((aQ[j] + bqv[mh][j]) * ATTN_SCALE);
                pk[j] = f2bf(aK[j] + bkv[mh][j]);
            }
            *(s16x4*)&g_q[qkb + (size_t)n*32 + mh*16 + lg*4] = pq;
            *(s16x4*)&g_k[qkb + (size_t)n*32 + mh*16 + lg*4] = pk;
            #pragma unroll
            for (int j = 0; j < 4; ++j)
                g_v[vb + (size_t)(mh*16 + lg*4 + j)*HWSZ + n] = f2bf(aV[j] + bvv[mh][j]);
        }
    }
}

// ---------------- attention: key-split partials, 4 independent waves/block ----------------
// block = 256 thr = 4 waves, zero sync. All 4 waves: same bg, same 16-q tile,
// the 4 key-split segments. Grid 16bg x 144qt = 2304 blocks -> VGPR-limited occ.
__global__ __launch_bounds__(256) void attn_mfma()
{
    __shared__ __align__(16) short p_lds[4][16][72];

    int tid  = threadIdx.x;
    int lane = tid & 63;
    int ks   = tid >> 6;             // wave = key-split segment
    int l15 = lane & 15;
    int lg  = lane >> 4;
    int bg = blockIdx.x & 15;        // XCD clustering: bg, bg+8 per XCD
    int qt = blockIdx.x >> 4;        // 0..143
    int k0 = ks * KSEG;

    const short* qg = g_q + (size_t)bg * HWSZ * DD;
    const short* kg = g_k + (size_t)bg * HWSZ * DD;
    const short* vg = g_v + (size_t)bg * DD * HWSZ;

    bf16x8 aq = *(const bf16x8*)&qg[(size_t)(qt*16 + l15)*32 + lg*8];

    f32x4 oc0 = {0.f,0.f,0.f,0.f}, oc1 = {0.f,0.f,0.f,0.f};
    const f32x4 zero = {0.f,0.f,0.f,0.f};
    float lsum = 0.f;

    bf16x8 ck[4], cv[4];
    #pragma unroll
    for (int kb = 0; kb < 4; ++kb)
        ck[kb] = *(const bf16x8*)&kg[(size_t)(k0 + kb*16 + l15)*32 + lg*8];
    #pragma unroll
    for (int h = 0; h < 2; ++h)
        #pragma unroll
        for (int w = 0; w < 2; ++w)
            cv[h*2+w] = *(const bf16x8*)&vg[(size_t)(w*16 + l15)*HWSZ + k0 + h*32 + lg*8];

    for (int t = 0; t < KSEG/64; ++t) {
        int mm = k0 + ((t + 1 < KSEG/64) ? (t + 1) * 64 : 0);
        bf16x8 nk[4], nv[4];
        #pragma unroll
        for (int kb = 0; kb < 4; ++kb)
            nk[kb] = *(const bf16x8*)&kg[(size_t)(mm + kb*16 + l15)*32 + lg*8];
        #pragma unroll
        for (int h = 0; h < 2; ++h)
            #pragma unroll
            for (int w = 0; w < 2; ++w)
                nv[h*2+w] = *(const bf16x8*)&vg[(size_t)(w*16 + l15)*HWSZ + mm + h*32 + lg*8];

        // S^T = K·Q^T : lane holds S[q=l15][k=kb*16+lg*4+j]
        f32x4 s[4];
        #pragma unroll
        for (int kb = 0; kb < 4; ++kb)
            s[kb] = __builtin_amdgcn_mfma_f32_16x16x32_bf16(ck[kb], aq, zero, 0, 0, 0);

        // p = exp2(s); lane-local denominator; cvt_pk pack; 8B DS writes
        #pragma unroll
        for (int kb = 0; kb < 4; ++kb) {
            float p0 = exp2f(s[kb][0]), p1 = exp2f(s[kb][1]);
            float p2 = exp2f(s[kb][2]), p3 = exp2f(s[kb][3]);
            lsum += (p0 + p1) + (p2 + p3);
            uint2 w2;
            w2.x = cvt_pk_bf16(p0, p1);
            w2.y = cvt_pk_bf16(p2, p3);
            *(uint2*)&p_lds[ks][l15][kb*16 + lg*4] = w2;
        }

        // PV (wave-private LDS region, no barrier)
        #pragma unroll
        for (int half = 0; half < 2; ++half) {
            bf16x8 pa = *(const bf16x8*)&p_lds[ks][l15][half*32 + lg*8];
            oc0 = __builtin_amdgcn_mfma_f32_16x16x32_bf16(cv[half*2+0], pa, oc0, 0, 0, 0);
            oc1 = __builtin_amdgcn_mfma_f32_16x16x32_bf16(cv[half*2+1], pa, oc1, 0, 0, 0);
        }

        #pragma unroll
        for (int kb = 0; kb < 4; ++kb) ck[kb] = nk[kb];
        #pragma unroll
        for (int i = 0; i < 4; ++i) cv[i] = nv[i];
    }

    // denominator over this split (q = l15 column, across lg)
    lsum += __shfl_xor(lsum, 16, 64);
    lsum += __shfl_xor(lsum, 32, 64);

    int n = qt * 16 + l15;
    size_t pb = (size_t)(ks * NBG + bg) * DD * HWSZ;
    #pragma unroll
    for (int j = 0; j < 4; ++j) {
        g_po[pb + (size_t)(lg*4 + j) * HWSZ + n]      = oc0[j];
        g_po[pb + (size_t)(16 + lg*4 + j) * HWSZ + n] = oc1[j];
    }
    if (lg == 0) g_pl[(size_t)(ks * NBG + bg) * HWSZ + n] = lsum;
}

// ---------------- combine partials + BN (batch stats) + affine + ReLU ----------------
__global__ __launch_bounds__(256) void bn_relu(
    const float* __restrict__ gamma, const float* __restrict__ beta,
    float* __restrict__ out)
{
    __shared__ float vbuf[2][HWSZ];           // combined attention output, 18.4 KB
    __shared__ float rs[4], rss[4];
    __shared__ float smean, sinv;
    int c = blockIdx.x;
    int tid = threadIdx.x;
    int g = c >> 5, d = c & 31;
    int bg0 = g, bg1 = 8 + g;                 // b=0,1

    float s = 0.f, ss = 0.f;
    for (int i = tid; i < HWSZ; i += 256) {
        float n0 = 0.f, d0 = 0.f, n1 = 0.f, d1 = 0.f;
        #pragma unroll
        for (int ks = 0; ks < KSPLIT; ++ks) {
            n0 += g_po[((size_t)(ks*NBG + bg0) * DD + d) * HWSZ + i];
            d0 += g_pl[(size_t)(ks*NBG + bg0) * HWSZ + i];
            n1 += g_po[((size_t)(ks*NBG + bg1) * DD + d) * HWSZ + i];
            d1 += g_pl[(size_t)(ks*NBG + bg1) * HWSZ + i];
        }
        float v0 = n0 / d0, v1 = n1 / d1;
        vbuf[0][i] = v0; vbuf[1][i] = v1;
        s += v0 + v1;
        ss += v0 * v0 + v1 * v1;
    }
    #pragma unroll
    for (int off = 32; off; off >>= 1) {
        s  += __shfl_down(s, off, 64);
        ss += __shfl_down(ss, off, 64);
    }
    int wid = tid >> 6, lane = tid & 63;
    if (lane == 0) { rs[wid] = s; rss[wid] = ss; }
    __syncthreads();
    if (tid == 0) {
        float ts  = rs[0] + rs[1] + rs[2] + rs[3];
        float tss = rss[0] + rss[1] + rss[2] + rss[3];
        float mean = ts / (float)NHW;
        float var  = tss / (float)NHW - mean * mean;
        smean = mean;
        sinv  = rsqrtf(var + 1e-5f);
    }
    __syncthreads();
    float mean = smean, inv = sinv;
    float ga = gamma[c], be = beta[c];
    float* out0 = out + (size_t)c * HWSZ;
    float* out1 = out + (size_t)(CC + c) * HWSZ;
    for (int i = tid; i < HWSZ; i += 256) {
        float v0 = (vbuf[0][i] - mean) * inv * ga + be;
        float v1 = (vbuf[1][i] - mean) * inv * ga + be;
        out0[i] = fmaxf(v0, 0.f);
        out1[i] = fmaxf(v1, 0.f);
    }
}

extern "C" void kernel_launch(void* const* d_in, const int* in_sizes, int n_in,
                              void* d_out, int out_size, void* d_ws, size_t ws_size,
                              hipStream_t stream)
{
    const float* x     = (const float*)d_in[0];
    const float* Wq    = (const float*)d_in[1];
    const float* bq    = (const float*)d_in[2];
    const float* Wk    = (const float*)d_in[3];
    const float* bk    = (const float*)d_in[4];
    const float* Wv    = (const float*)d_in[5];
    const float* bv    = (const float*)d_in[6];
    const float* gamma = (const float*)d_in[7];
    const float* beta  = (const float*)d_in[8];
    float* out = (float*)d_out;

    pack_w<<<(CC*DD*9 + 2*CC*DD + 255) / 256, 256, 0, stream>>>(Wq, Wk, Wv);
    conv_mfma<<<NBG * 9, 256, 0, stream>>>(x, bq, bk, bv);
    attn_mfma<<<NBG * 144, 256, 0, stream>>>();
    bn_relu<<<CC, 256, 0, stream>>>(gamma, beta, out);
}